// Round 8
// baseline (141.191 us; speedup 1.0000x reference)
//
#include <hip/hip_runtime.h>
#include <hip/hip_fp16.h>

// Problem constants (match reference)
#define BB 8
#define NN 1024
#define IN_DIM 512
#define HH 8
#define SUP 64
#define HS (HH * SUP)   // 512

// LDS row strides in halves. MUST be ≡ 2 mod 4 (odd dword stride) so the
// MFMA fragment reads (quad*8-half offsets) spread across banks: with stride
// 40/136 (dword stride ≡ 0 mod 4) banks collapse to 8 → ~8-way conflicts.
#define XS_STRIDE 34     // 17 dwords, odd
#define VT_STRIDE 130    // 65 dwords, odd

typedef _Float16 half8 __attribute__((ext_vector_type(8)));
typedef _Float16 half2v __attribute__((ext_vector_type(2)));
typedef float floatx4 __attribute__((ext_vector_type(4)));

// ---------------------------------------------------------------------------
// kW: W[h][i][o] fp32 -> Wt[h][o][i] fp16 (transpose + downconvert).
// grid 64, block 256.
// ---------------------------------------------------------------------------
__global__ __launch_bounds__(256) void kW(const float* __restrict__ W,
                                          _Float16* __restrict__ Wt) {
    __shared__ float tile[64][65];
    const int it = blockIdx.x & 7;
    const int h  = blockIdx.x >> 3;
    const int t  = threadIdx.x;
    {
        const int i  = t >> 2;
        const int o0 = (t & 3) * 16;
        const float* src = W + ((size_t)h * IN_DIM + it * 64 + i) * SUP + o0;
#pragma unroll
        for (int j = 0; j < 4; j++) {
            float4 v = ((const float4*)src)[j];
            tile[i][o0 + j * 4 + 0] = v.x;
            tile[i][o0 + j * 4 + 1] = v.y;
            tile[i][o0 + j * 4 + 2] = v.z;
            tile[i][o0 + j * 4 + 3] = v.w;
        }
    }
    __syncthreads();
    {
        const int o  = t >> 2;
        const int i0 = (t & 3) * 16;
        _Float16 buf[16];
#pragma unroll
        for (int j = 0; j < 16; j++) buf[j] = (_Float16)tile[i0 + j][o];
        _Float16* dst = Wt + ((size_t)h * SUP + o) * IN_DIM + it * 64 + i0;
        *(half8*)dst       = *(half8*)buf;
        *(half8*)(dst + 8) = *(half8*)(buf + 8);
    }
}

// ---------------------------------------------------------------------------
// k1: grid-split.
//   blockIdx.x < 16: projection, TWO heads per block. Per (b, head-pair):
//     P[1024,128] = X_b @ [W_h0 | W_h1]. LDS double-buffered, 1 barrier/slab,
//     8 MFMA per slab per wave. Epilogue: Pt[bh][o][n] fp16, s/t from fp32
//     accumulators (shuffle-reduce), per-tile tmax for both heads.
//   blockIdx.x >= 16: pack A fp32 (0/1) -> bitmask Am[row][128 B] (ballot).
//     Memory-bound; overlaps the MFMA-bound proj blocks.
// grid (16+8, 32), block 256 (4 waves).
// ---------------------------------------------------------------------------
__global__ __launch_bounds__(256) void k1_proj(const float* __restrict__ X,
                                               const _Float16* __restrict__ Wt,
                                               const float* __restrict__ A,
                                               unsigned char* __restrict__ Am,
                                               const float* __restrict__ w1,
                                               const float* __restrict__ b1,
                                               const float* __restrict__ w2,
                                               const float* __restrict__ b2,
                                               _Float16* __restrict__ Pt,
                                               float* __restrict__ s_g,
                                               float* __restrict__ t_g,
                                               float* __restrict__ tmax16) {
    __shared__ __align__(16) _Float16 xs[2][64 * XS_STRIDE];    // X tile [n][k]
    __shared__ __align__(16) _Float16 wsh[2][128 * XS_STRIDE];  // W tile [o2][k] (2 heads)
    __shared__ __align__(16) _Float16 po[128 * 72];             // epilogue [o2][n]
    __shared__ float tred[2][64];

    const int t    = threadIdx.x;
    const int wave = t >> 6;
    const int lane = t & 63;

    if (blockIdx.x >= 16) {
        // ---- pack A (bitmask) ----
        const int idx = (blockIdx.x - 16) * 32 + blockIdx.y;   // 0..255
#pragma unroll
        for (int i = 0; i < 8; i++) {
            const int row = idx * 32 + wave * 8 + i;           // 0..8191
            const float* arow = A + (size_t)row * NN;
            unsigned long long keep = 0;
#pragma unroll
            for (int g = 0; g < 16; g++) {
                float a = arow[g * 64 + lane];
                unsigned long long bal = __ballot(a > 0.5f);
                if (lane == g) keep = bal;
            }
            if (lane < 16)
                *(unsigned long long*)(Am + (size_t)row * 128 + lane * 8) = keep;
        }
        return;
    }

    // ---- projection, 2 heads ----
    const int bp  = blockIdx.y;        // 0..31
    const int b   = bp >> 2;
    const int h0  = (bp & 3) * 2;
    const int bh0 = b * 8 + h0;
    const int n0  = blockIdx.x * 64;
    const int quad = lane >> 4;
    const int l15  = lane & 15;
    const int row  = t >> 2;           // X staging row 0..63
    const int koff = (t & 3) * 8;      // X staging k offset
    const int wrow  = t >> 1;          // W staging row 0..127 (2 heads)
    const int wkoff = (t & 1) * 16;    // W staging k offset

    floatx4 acc[8];
#pragma unroll
    for (int i = 0; i < 8; i++) acc[i] = {0.f, 0.f, 0.f, 0.f};

    float w1v[8], w2v[8];
#pragma unroll
    for (int ct = 0; ct < 8; ct++) {           // ct*16 spans both heads' 128 weights
        w1v[ct] = w1[h0 * 64 + ct * 16 + l15];
        w2v[ct] = w2[h0 * 64 + ct * 16 + l15];
    }
    const float b1h0 = b1[h0], b1h1 = b1[h0 + 1];
    const float b2h0 = b2[h0], b2h1 = b2[h0 + 1];

    const float*    xbase = X + ((size_t)b * NN + n0 + row) * IN_DIM + koff;
    const _Float16* wbase = Wt + ((size_t)(h0 * SUP) + wrow) * IN_DIM + wkoff;

    // prefetch slab 0
    float4 xa = ((const float4*)xbase)[0];
    float4 xb = ((const float4*)xbase)[1];
    half8  wv0 = ((const half8*)wbase)[0];
    half8  wv1 = *(const half8*)(wbase + 8);

    for (int it = 0; it < 16; it++) {
        const int cur = it & 1;
        {
            _Float16 xh[8] = {(_Float16)xa.x, (_Float16)xa.y, (_Float16)xa.z, (_Float16)xa.w,
                              (_Float16)xb.x, (_Float16)xb.y, (_Float16)xb.z, (_Float16)xb.w};
            *(half8*)&xs[cur][row * XS_STRIDE + koff] = *(half8*)xh;
            *(half8*)&wsh[cur][wrow * XS_STRIDE + wkoff]     = wv0;
            *(half8*)&wsh[cur][wrow * XS_STRIDE + wkoff + 8] = wv1;
        }
        __syncthreads();   // tile `it` visible; prior reads of buf `cur` drained
        if (it < 15) {
            const float* src = xbase + (it + 1) * 32;
            xa = ((const float4*)src)[0];
            xb = ((const float4*)src)[1];
            wv0 = *(const half8*)(wbase + (it + 1) * 32);
            wv1 = *(const half8*)(wbase + (it + 1) * 32 + 8);
        }
        half8 af = *(const half8*)&xs[cur][(wave * 16 + l15) * XS_STRIDE + quad * 8];
#pragma unroll
        for (int ct = 0; ct < 8; ct++) {
            half8 bf = *(const half8*)&wsh[cur][(ct * 16 + l15) * XS_STRIDE + quad * 8];
            acc[ct] = __builtin_amdgcn_mfma_f32_16x16x32_f16(af, bf, acc[ct], 0, 0, 0);
        }
        // no second barrier: next write goes to the other buffer
    }
    __syncthreads();

    // epilogue 1: po[o2][n] fp16 tile + s/t for both heads
#pragma unroll
    for (int ct = 0; ct < 8; ct++) {
#pragma unroll
        for (int r = 0; r < 4; r++) {
            int o = ct * 16 + l15;                 // 0..127
            int n = wave * 16 + quad * 4 + r;
            po[o * 72 + n] = (_Float16)acc[ct][r];
        }
    }
#pragma unroll
    for (int r = 0; r < 4; r++) {
        float sp0 = 0.f, tp0 = 0.f, sp1 = 0.f, tp1 = 0.f;
#pragma unroll
        for (int ct = 0; ct < 4; ct++) {
            sp0 += acc[ct][r] * w1v[ct];
            tp0 += acc[ct][r] * w2v[ct];
            sp1 += acc[ct + 4][r] * w1v[ct + 4];
            tp1 += acc[ct + 4][r] * w2v[ct + 4];
        }
#pragma unroll
        for (int off = 1; off < 16; off <<= 1) {
            sp0 += __shfl_xor(sp0, off);
            tp0 += __shfl_xor(tp0, off);
            sp1 += __shfl_xor(sp1, off);
            tp1 += __shfl_xor(tp1, off);
        }
        if (l15 == 0) {
            const int n = wave * 16 + quad * 4 + r;
            s_g[(size_t)bh0 * NN + n0 + n] = sp0 + b1h0;
            float tv0 = tp0 + b2h0;
            t_g[(size_t)bh0 * NN + n0 + n] = tv0;
            tred[0][n] = tv0;
            s_g[(size_t)(bh0 + 1) * NN + n0 + n] = sp1 + b1h1;
            float tv1 = tp1 + b2h1;
            t_g[(size_t)(bh0 + 1) * NN + n0 + n] = tv1;
            tred[1][n] = tv1;
        }
    }
    __syncthreads();
    // epilogue 2: coalesced Pt store (both heads; flat index bh0*64 + orow)
    {
        const int orow = t >> 1;          // 0..127
        const int nof  = (t & 1) * 32;
        _Float16* dst = Pt + ((size_t)(bh0 * SUP + orow)) * NN + n0 + nof;
        const _Float16* src = &po[orow * 72 + nof];
        *(half8*)dst        = *(const half8*)src;
        *(half8*)(dst + 8)  = *(const half8*)(src + 8);
        *(half8*)(dst + 16) = *(const half8*)(src + 16);
        *(half8*)(dst + 24) = *(const half8*)(src + 24);
    }
    if (t == 0) {
        float m0 = -1e30f, m1 = -1e30f;
#pragma unroll
        for (int i = 0; i < 64; i++) {
            m0 = fmaxf(m0, tred[0][i]);
            m1 = fmaxf(m1, tred[1][i]);
        }
        tmax16[bh0 * 16 + blockIdx.x] = m0;
        tmax16[(bh0 + 1) * 16 + blockIdx.x] = m1;
    }
}

// ---------------------------------------------------------------------------
// k2: fused masked-softmax attention + aggregation, packed-fp16 logit math.
// Per block: one (b,h), 128 query rows, 512 threads (8 waves).
// Double-buffered 128-key V^T tiles, ONE barrier per tile. Mask bits expanded
// via 256-entry LDS LUT; Z via v_dot2_f32_f16 + shfl.
// grid (N/128, B*H), block 512.
// ---------------------------------------------------------------------------
__global__ __launch_bounds__(512) void k2_attn(const unsigned char* __restrict__ Am,
                                               const _Float16* __restrict__ Pt,
                                               const float* __restrict__ s_g,
                                               const float* __restrict__ t_g,
                                               const float* __restrict__ tmax16,
                                               float* __restrict__ out) {
    __shared__ __align__(16) _Float16 vts[2][64 * VT_STRIDE];  // V^T tile [o][m]
    __shared__ __align__(16) unsigned t2l[NN / 2];             // t as packed half2 (2 KB)
    __shared__ __align__(16) uint4 lutm[256];                  // bit->fp16-mask LUT (4 KB)

    const int bh = blockIdx.y;
    const int b  = bh >> 3;
    const int h  = bh & 7;
    const int n0 = blockIdx.x * 128;
    const int t    = threadIdx.x;
    const int wave = t >> 6;
    const int lane = t & 63;
    const int quad = lane >> 4;
    const int l15  = lane & 15;
    const int row4 = t >> 3;   // staging o-row 0..63
    const int seg  = t & 7;    // staging segment (16 keys each)

    // stage t as packed fp16 pairs
    {
        float2 tv2 = ((const float2*)(t_g + (size_t)bh * NN))[t];
        half2v tp = {(_Float16)tv2.x, (_Float16)tv2.y};
        t2l[t] = *(unsigned*)&tp;
    }
    // build mask-expansion LUT: byte -> 4 words of per-half 0xFFFF masks
    if (t < 256) {
        unsigned e = (unsigned)t;
        uint4 v;
        v.x = ((e & 1u)   ? 0xFFFFu : 0u) | ((e & 2u)   ? 0xFFFF0000u : 0u);
        v.y = ((e & 4u)   ? 0xFFFFu : 0u) | ((e & 8u)   ? 0xFFFF0000u : 0u);
        v.z = ((e & 16u)  ? 0xFFFFu : 0u) | ((e & 32u)  ? 0xFFFF0000u : 0u);
        v.w = ((e & 64u)  ? 0xFFFFu : 0u) | ((e & 128u) ? 0xFFFF0000u : 0u);
        lutm[t] = v;
    }

    float tmax = -1e30f;
#pragma unroll
    for (int i = 0; i < 16; i++) tmax = fmaxf(tmax, tmax16[bh * 16 + i]);

    const int myrow = wave * 16 + l15;                 // this lane's query row (0..127)
    const float sv = s_g[(size_t)bh * NN + n0 + myrow];
    const float xc = sv + tmax;
    const float cv = fmaxf(xc, 0.01f * xc);            // c >= row max logit
    const float l2e = 1.44269504f;
    const _Float16 sc1h = (_Float16)((sv - cv) * l2e);       // (s-c)*log2e
    const _Float16 sc2h = (_Float16)(-0.99f * cv * l2e);     // -0.99*c*log2e
    const half2v sc1 = {sc1h, sc1h};
    const half2v sc2 = {sc2h, sc2h};
    const half2v vl2e = {(_Float16)l2e, (_Float16)l2e};
    const half2v v001 = {(_Float16)0.01f, (_Float16)0.01f};
    const half2v ones2 = {(_Float16)1.0f, (_Float16)1.0f};

    floatx4 acc[4];
#pragma unroll
    for (int i = 0; i < 4; i++) acc[i] = {0.f, 0.f, 0.f, 0.f};
    float zp = 0.f;

    // V^T staging pointer + prefetch tile 0
    const _Float16* pb = Pt + ((size_t)bh * SUP + row4) * NN + seg * 16;
    half8 v0 = ((const half8*)pb)[0];
    half8 v1 = ((const half8*)pb)[1];
    // mask row pointer + prefetch tile 0
    const uint4* mrow = (const uint4*)(Am + ((size_t)b * NN + n0 + myrow) * 128);
    uint4 mcur = mrow[0];

    for (int mt = 0; mt < 8; mt++) {
        const int cur = mt & 1;
        {
            _Float16* d = &vts[cur][row4 * VT_STRIDE + seg * 16];
            ((half8*)d)[0] = v0;
            ((half8*)d)[1] = v1;
        }
        __syncthreads();   // tile mt (and t2l/lutm on mt=0) visible
        uint4 mnext;
        if (mt < 7) {
            const _Float16* p = pb + (mt + 1) * 128;
            v0 = ((const half8*)p)[0];
            v1 = ((const half8*)p)[1];
            mnext = mrow[mt + 1];
        }
        const unsigned mw[4] = {mcur.x, mcur.y, mcur.z, mcur.w};
#pragma unroll
        for (int kk = 0; kk < 4; kk++) {
            const unsigned mbyte = (mw[kk] >> (quad * 8)) & 0xffu;
            uint4 mx = lutm[mbyte];
            const unsigned mxw[4] = {mx.x, mx.y, mx.z, mx.w};
            uint4 tw = *(const uint4*)&t2l[mt * 64 + kk * 16 + quad * 4];
            union { uint4 u; half2v h[4]; } tt; tt.u = tw;
            union { half2v h[4]; half8 h8; } wbu;
#pragma unroll
            for (int p = 0; p < 4; p++) {
                half2v y = tt.h[p] * vl2e + sc1;                    // (x-c)*log2e
                half2v w = y * v001 + sc2;                          // (.01x-c)*log2e
                half2v z = __builtin_elementwise_max(y, w);         // lrelu branch merge
                __half2 zz = *(__half2*)&z;
                __half2 ee = h2exp2(zz);                            // 2^z = e^(l-c)
                unsigned eb = (*(unsigned*)&ee) & mxw[p];           // mask
                half2v e2 = *(half2v*)&eb;
#if __has_builtin(__builtin_amdgcn_fdot2)
                zp = __builtin_amdgcn_fdot2(e2, ones2, zp, false);
#else
                zp += (float)e2.x + (float)e2.y;
#endif
                wbu.h[p] = e2;
            }
            half8 af = wbu.h8;
#pragma unroll
            for (int ct = 0; ct < 4; ct++) {
                half8 bf = *(const half8*)&vts[cur][(ct * 16 + l15) * VT_STRIDE + kk * 32 + quad * 8];
                acc[ct] = __builtin_amdgcn_mfma_f32_16x16x32_f16(af, bf, acc[ct], 0, 0, 0);
            }
        }
        if (mt < 7) mcur = mnext;
    }

    // Z reduction across quads, distribute 1/Z by shfl
    zp += __shfl_xor(zp, 16);
    zp += __shfl_xor(zp, 32);
    const float rzown = 1.0f / zp;

    // epilogue: out[b][n][h*64+o] = relu(acc / Z)
#pragma unroll
    for (int r = 0; r < 4; r++) {
        const int rr = wave * 16 + quad * 4 + r;
        const float rz = __shfl(rzown, quad * 20 + r);
#pragma unroll
        for (int ct = 0; ct < 4; ct++) {
            float v = acc[ct][r] * rz;
            v = v > 0.f ? v : 0.f;
            out[((size_t)b * NN + n0 + rr) * HS + h * SUP + ct * 16 + l15] = v;
        }
    }
}

// ---------------------------------------------------------------------------
extern "C" void kernel_launch(void* const* d_in, const int* in_sizes, int n_in,
                              void* d_out, int out_size, void* d_ws, size_t ws_size,
                              hipStream_t stream) {
    const float* A  = (const float*)d_in[0];
    const float* X  = (const float*)d_in[1];
    const float* W  = (const float*)d_in[2];
    const float* w1 = (const float*)d_in[3];
    const float* b1 = (const float*)d_in[4];
    const float* w2 = (const float*)d_in[5];
    const float* b2 = (const float*)d_in[6];
    float* out = (float*)d_out;

    char* ws = (char*)d_ws;
    _Float16*      Wt     = (_Float16*)(ws);                  // 524288 B
    _Float16*      Pt     = (_Float16*)(ws + 524288);         // 8388608 B
    float*         s_g    = (float*)(ws + 8912896);           // 262144 B
    float*         t_g    = (float*)(ws + 9175040);           // 262144 B
    float*         tmax16 = (float*)(ws + 9437184);           // 4096 B
    unsigned char* Am     = (unsigned char*)(ws + 9441280);   // 1048576 B

    hipLaunchKernelGGL(kW, dim3(64), dim3(256), 0, stream, W, Wt);
    hipLaunchKernelGGL(k1_proj, dim3(16 + 8, 32), dim3(256), 0, stream,
                       X, Wt, A, Am, w1, b1, w2, b2, Pt, s_g, t_g, tmax16);
    hipLaunchKernelGGL(k2_attn, dim3(NN / 128, BB * HH), dim3(512), 0, stream,
                       Am, Pt, s_g, t_g, tmax16, out);
}

// Round 9
// 132.928 us; speedup vs baseline: 1.0622x; 1.0622x over previous
//
#include <hip/hip_runtime.h>
#include <hip/hip_fp16.h>

// Problem constants (match reference)
#define BB 8
#define NN 1024
#define IN_DIM 512
#define HH 8
#define SUP 64
#define HS (HH * SUP)   // 512

// LDS row strides in halves. MUST be a multiple of 8 halves (16 B) so
// half8 LDS accesses stay b128 (R8 lesson: stride 34 split them into b32,
// -7.5us). 40/136 measured best (R7).
#define XS_STRIDE 40
#define VT_STRIDE 136

typedef _Float16 half8 __attribute__((ext_vector_type(8)));
typedef _Float16 half2v __attribute__((ext_vector_type(2)));
typedef float floatx4 __attribute__((ext_vector_type(4)));

// ---------------------------------------------------------------------------
// kW: W[h][i][o] fp32 -> Wt[h][o][i] fp16 (transpose + downconvert).
// grid 64, block 256.
// ---------------------------------------------------------------------------
__global__ __launch_bounds__(256) void kW(const float* __restrict__ W,
                                          _Float16* __restrict__ Wt) {
    __shared__ float tile[64][65];
    const int it = blockIdx.x & 7;
    const int h  = blockIdx.x >> 3;
    const int t  = threadIdx.x;
    {
        const int i  = t >> 2;
        const int o0 = (t & 3) * 16;
        const float* src = W + ((size_t)h * IN_DIM + it * 64 + i) * SUP + o0;
#pragma unroll
        for (int j = 0; j < 4; j++) {
            float4 v = ((const float4*)src)[j];
            tile[i][o0 + j * 4 + 0] = v.x;
            tile[i][o0 + j * 4 + 1] = v.y;
            tile[i][o0 + j * 4 + 2] = v.z;
            tile[i][o0 + j * 4 + 3] = v.w;
        }
    }
    __syncthreads();
    {
        const int o  = t >> 2;
        const int i0 = (t & 3) * 16;
        _Float16 buf[16];
#pragma unroll
        for (int j = 0; j < 16; j++) buf[j] = (_Float16)tile[i0 + j][o];
        _Float16* dst = Wt + ((size_t)h * SUP + o) * IN_DIM + it * 64 + i0;
        *(half8*)dst       = *(half8*)buf;
        *(half8*)(dst + 8) = *(half8*)(buf + 8);
    }
}

// ---------------------------------------------------------------------------
// k1: 1-D grid, XCD-swizzled.
//   bid < 512: projection, TWO heads per block. flat-id ≡ b (mod 8) so all
//     64 blocks sharing batch b land on one XCD -> X slab (2 MB) is L2-hot.
//     b = bid&7, j = bid>>3, hp = j&3, tile = j>>2.
//   bid >= 512: pack A fp32 (0/1) -> bitmask Am[row][128 B] (ballot).
// grid 768, block 256 (4 waves).
// ---------------------------------------------------------------------------
__global__ __launch_bounds__(256) void k1_proj(const float* __restrict__ X,
                                               const _Float16* __restrict__ Wt,
                                               const float* __restrict__ A,
                                               unsigned char* __restrict__ Am,
                                               const float* __restrict__ w1,
                                               const float* __restrict__ b1,
                                               const float* __restrict__ w2,
                                               const float* __restrict__ b2,
                                               _Float16* __restrict__ Pt,
                                               float* __restrict__ s_g,
                                               float* __restrict__ t_g,
                                               float* __restrict__ tmax16) {
    __shared__ __align__(16) _Float16 xs[2][64 * XS_STRIDE];    // X tile [n][k]
    __shared__ __align__(16) _Float16 wsh[2][128 * XS_STRIDE];  // W tile [o2][k]
    __shared__ __align__(16) _Float16 po[128 * 72];             // epilogue [o2][n]
    __shared__ float tred[2][64];

    const int bid  = blockIdx.x;
    const int t    = threadIdx.x;
    const int wave = t >> 6;
    const int lane = t & 63;

    if (bid >= 512) {
        // ---- pack A (bitmask) ----
        const int idx = bid - 512;                             // 0..255
#pragma unroll
        for (int i = 0; i < 8; i++) {
            const int row = idx * 32 + wave * 8 + i;           // 0..8191
            const float* arow = A + (size_t)row * NN;
            unsigned long long keep = 0;
#pragma unroll
            for (int g = 0; g < 16; g++) {
                float a = arow[g * 64 + lane];
                unsigned long long bal = __ballot(a > 0.5f);
                if (lane == g) keep = bal;
            }
            if (lane < 16)
                *(unsigned long long*)(Am + (size_t)row * 128 + lane * 8) = keep;
        }
        return;
    }

    // ---- projection, 2 heads; XCD-swizzled decode ----
    const int b    = bid & 7;
    const int j    = bid >> 3;         // 0..63
    const int h0   = (j & 3) * 2;
    const int bh0  = b * 8 + h0;
    const int n0   = (j >> 2) * 64;    // 16 tiles
    const int quad = lane >> 4;
    const int l15  = lane & 15;
    const int row  = t >> 2;           // X staging row 0..63
    const int koff = (t & 3) * 8;      // X staging k offset
    const int wrow  = t >> 1;          // W staging row 0..127 (2 heads)
    const int wkoff = (t & 1) * 16;    // W staging k offset

    floatx4 acc[8];
#pragma unroll
    for (int i = 0; i < 8; i++) acc[i] = {0.f, 0.f, 0.f, 0.f};

    float w1v[8], w2v[8];
#pragma unroll
    for (int ct = 0; ct < 8; ct++) {           // ct*16 spans both heads' 128 weights
        w1v[ct] = w1[h0 * 64 + ct * 16 + l15];
        w2v[ct] = w2[h0 * 64 + ct * 16 + l15];
    }
    const float b1h0 = b1[h0], b1h1 = b1[h0 + 1];
    const float b2h0 = b2[h0], b2h1 = b2[h0 + 1];

    const float*    xbase = X + ((size_t)b * NN + n0 + row) * IN_DIM + koff;
    const _Float16* wbase = Wt + ((size_t)(h0 * SUP) + wrow) * IN_DIM + wkoff;

    // prefetch slab 0
    float4 xa = ((const float4*)xbase)[0];
    float4 xb = ((const float4*)xbase)[1];
    half8  wv0 = ((const half8*)wbase)[0];
    half8  wv1 = *(const half8*)(wbase + 8);

    for (int it = 0; it < 16; it++) {
        const int cur = it & 1;
        {
            _Float16 xh[8] = {(_Float16)xa.x, (_Float16)xa.y, (_Float16)xa.z, (_Float16)xa.w,
                              (_Float16)xb.x, (_Float16)xb.y, (_Float16)xb.z, (_Float16)xb.w};
            *(half8*)&xs[cur][row * XS_STRIDE + koff] = *(half8*)xh;
            *(half8*)&wsh[cur][wrow * XS_STRIDE + wkoff]     = wv0;
            *(half8*)&wsh[cur][wrow * XS_STRIDE + wkoff + 8] = wv1;
        }
        __syncthreads();   // tile `it` visible; prior reads of buf `cur` drained
        if (it < 15) {
            const float* src = xbase + (it + 1) * 32;
            xa = ((const float4*)src)[0];
            xb = ((const float4*)src)[1];
            wv0 = *(const half8*)(wbase + (it + 1) * 32);
            wv1 = *(const half8*)(wbase + (it + 1) * 32 + 8);
        }
        half8 af = *(const half8*)&xs[cur][(wave * 16 + l15) * XS_STRIDE + quad * 8];
#pragma unroll
        for (int ct = 0; ct < 8; ct++) {
            half8 bf = *(const half8*)&wsh[cur][(ct * 16 + l15) * XS_STRIDE + quad * 8];
            acc[ct] = __builtin_amdgcn_mfma_f32_16x16x32_f16(af, bf, acc[ct], 0, 0, 0);
        }
        // no second barrier: next write goes to the other buffer
    }
    __syncthreads();

    // epilogue 1: po[o2][n] fp16 tile + s/t for both heads
#pragma unroll
    for (int ct = 0; ct < 8; ct++) {
#pragma unroll
        for (int r = 0; r < 4; r++) {
            int o = ct * 16 + l15;                 // 0..127
            int n = wave * 16 + quad * 4 + r;
            po[o * 72 + n] = (_Float16)acc[ct][r];
        }
    }
#pragma unroll
    for (int r = 0; r < 4; r++) {
        float sp0 = 0.f, tp0 = 0.f, sp1 = 0.f, tp1 = 0.f;
#pragma unroll
        for (int ct = 0; ct < 4; ct++) {
            sp0 += acc[ct][r] * w1v[ct];
            tp0 += acc[ct][r] * w2v[ct];
            sp1 += acc[ct + 4][r] * w1v[ct + 4];
            tp1 += acc[ct + 4][r] * w2v[ct + 4];
        }
#pragma unroll
        for (int off = 1; off < 16; off <<= 1) {
            sp0 += __shfl_xor(sp0, off);
            tp0 += __shfl_xor(tp0, off);
            sp1 += __shfl_xor(sp1, off);
            tp1 += __shfl_xor(tp1, off);
        }
        if (l15 == 0) {
            const int n = wave * 16 + quad * 4 + r;
            s_g[(size_t)bh0 * NN + n0 + n] = sp0 + b1h0;
            float tv0 = tp0 + b2h0;
            t_g[(size_t)bh0 * NN + n0 + n] = tv0;
            tred[0][n] = tv0;
            s_g[(size_t)(bh0 + 1) * NN + n0 + n] = sp1 + b1h1;
            float tv1 = tp1 + b2h1;
            t_g[(size_t)(bh0 + 1) * NN + n0 + n] = tv1;
            tred[1][n] = tv1;
        }
    }
    __syncthreads();
    // epilogue 2: coalesced Pt store (both heads; flat index bh0*64 + orow)
    {
        const int orow = t >> 1;          // 0..127
        const int nof  = (t & 1) * 32;
        _Float16* dst = Pt + ((size_t)(bh0 * SUP + orow)) * NN + n0 + nof;
        const _Float16* src = &po[orow * 72 + nof];
        *(half8*)dst        = *(const half8*)src;
        *(half8*)(dst + 8)  = *(const half8*)(src + 8);
        *(half8*)(dst + 16) = *(const half8*)(src + 16);
        *(half8*)(dst + 24) = *(const half8*)(src + 24);
    }
    if (t == 0) {
        float m0 = -1e30f, m1 = -1e30f;
#pragma unroll
        for (int i = 0; i < 64; i++) {
            m0 = fmaxf(m0, tred[0][i]);
            m1 = fmaxf(m1, tred[1][i]);
        }
        tmax16[bh0 * 16 + (n0 >> 6)] = m0;
        tmax16[(bh0 + 1) * 16 + (n0 >> 6)] = m1;
    }
}

// ---------------------------------------------------------------------------
// k2: fused masked-softmax attention + aggregation, packed-fp16 logit math.
// 1-D grid 512, XCD-swizzled: flat-id ≡ h (mod 8) so all 8 n-tile blocks of
// a given bh (plus its 8 batches) stay on one XCD -> Pt slab (1 MB/XCD)
// is L2-hot. h = bid&7, b = (bid>>3)&7, tile = bid>>6.
// 128 query rows/block, 512 threads; dbuf V^T tiles, 1 barrier/tile;
// mask-bit LUT in LDS; Z via fdot2 + shfl.
// ---------------------------------------------------------------------------
__global__ __launch_bounds__(512) void k2_attn(const unsigned char* __restrict__ Am,
                                               const _Float16* __restrict__ Pt,
                                               const float* __restrict__ s_g,
                                               const float* __restrict__ t_g,
                                               const float* __restrict__ tmax16,
                                               float* __restrict__ out) {
    __shared__ __align__(16) _Float16 vts[2][64 * VT_STRIDE];  // V^T tile [o][m]
    __shared__ __align__(16) unsigned t2l[NN / 2];             // t as packed half2 (2 KB)
    __shared__ __align__(16) uint4 lutm[256];                  // bit->fp16-mask LUT (4 KB)

    const int bid = blockIdx.x;
    const int h   = bid & 7;
    const int b   = (bid >> 3) & 7;
    const int bh  = b * 8 + h;
    const int n0  = (bid >> 6) * 128;
    const int t    = threadIdx.x;
    const int wave = t >> 6;
    const int lane = t & 63;
    const int quad = lane >> 4;
    const int l15  = lane & 15;
    const int row4 = t >> 3;   // staging o-row 0..63
    const int seg  = t & 7;    // staging segment (16 keys each)

    // stage t as packed fp16 pairs
    {
        float2 tv2 = ((const float2*)(t_g + (size_t)bh * NN))[t];
        half2v tp = {(_Float16)tv2.x, (_Float16)tv2.y};
        t2l[t] = *(unsigned*)&tp;
    }
    // build mask-expansion LUT: byte -> 4 words of per-half 0xFFFF masks
    if (t < 256) {
        unsigned e = (unsigned)t;
        uint4 v;
        v.x = ((e & 1u)   ? 0xFFFFu : 0u) | ((e & 2u)   ? 0xFFFF0000u : 0u);
        v.y = ((e & 4u)   ? 0xFFFFu : 0u) | ((e & 8u)   ? 0xFFFF0000u : 0u);
        v.z = ((e & 16u)  ? 0xFFFFu : 0u) | ((e & 32u)  ? 0xFFFF0000u : 0u);
        v.w = ((e & 64u)  ? 0xFFFFu : 0u) | ((e & 128u) ? 0xFFFF0000u : 0u);
        lutm[t] = v;
    }

    float tmax = -1e30f;
#pragma unroll
    for (int i = 0; i < 16; i++) tmax = fmaxf(tmax, tmax16[bh * 16 + i]);

    const int myrow = wave * 16 + l15;                 // this lane's query row (0..127)
    const float sv = s_g[(size_t)bh * NN + n0 + myrow];
    const float xc = sv + tmax;
    const float cv = fmaxf(xc, 0.01f * xc);            // c >= row max logit
    const float l2e = 1.44269504f;
    const _Float16 sc1h = (_Float16)((sv - cv) * l2e);       // (s-c)*log2e
    const _Float16 sc2h = (_Float16)(-0.99f * cv * l2e);     // -0.99*c*log2e
    const half2v sc1 = {sc1h, sc1h};
    const half2v sc2 = {sc2h, sc2h};
    const half2v vl2e = {(_Float16)l2e, (_Float16)l2e};
    const half2v v001 = {(_Float16)0.01f, (_Float16)0.01f};
    const half2v ones2 = {(_Float16)1.0f, (_Float16)1.0f};

    floatx4 acc[4];
#pragma unroll
    for (int i = 0; i < 4; i++) acc[i] = {0.f, 0.f, 0.f, 0.f};
    float zp = 0.f;

    // V^T staging pointer + prefetch tile 0
    const _Float16* pb = Pt + ((size_t)bh * SUP + row4) * NN + seg * 16;
    half8 v0 = ((const half8*)pb)[0];
    half8 v1 = ((const half8*)pb)[1];
    // mask row pointer + prefetch tile 0
    const uint4* mrow = (const uint4*)(Am + ((size_t)b * NN + n0 + myrow) * 128);
    uint4 mcur = mrow[0];

    for (int mt = 0; mt < 8; mt++) {
        const int cur = mt & 1;
        {
            _Float16* d = &vts[cur][row4 * VT_STRIDE + seg * 16];
            ((half8*)d)[0] = v0;
            ((half8*)d)[1] = v1;
        }
        __syncthreads();   // tile mt (and t2l/lutm on mt=0) visible
        uint4 mnext;
        if (mt < 7) {
            const _Float16* p = pb + (mt + 1) * 128;
            v0 = ((const half8*)p)[0];
            v1 = ((const half8*)p)[1];
            mnext = mrow[mt + 1];
        }
        const unsigned mw[4] = {mcur.x, mcur.y, mcur.z, mcur.w};
#pragma unroll
        for (int kk = 0; kk < 4; kk++) {
            const unsigned mbyte = (mw[kk] >> (quad * 8)) & 0xffu;
            uint4 mx = lutm[mbyte];
            const unsigned mxw[4] = {mx.x, mx.y, mx.z, mx.w};
            uint4 tw = *(const uint4*)&t2l[mt * 64 + kk * 16 + quad * 4];
            union { uint4 u; half2v h[4]; } tt; tt.u = tw;
            union { half2v h[4]; half8 h8; } wbu;
#pragma unroll
            for (int p = 0; p < 4; p++) {
                half2v y = tt.h[p] * vl2e + sc1;                    // (x-c)*log2e
                half2v w = y * v001 + sc2;                          // (.01x-c)*log2e
                half2v z = __builtin_elementwise_max(y, w);         // lrelu branch merge
                __half2 zz = *(__half2*)&z;
                __half2 ee = h2exp2(zz);                            // 2^z = e^(l-c)
                unsigned eb = (*(unsigned*)&ee) & mxw[p];           // mask
                half2v e2 = *(half2v*)&eb;
#if __has_builtin(__builtin_amdgcn_fdot2)
                zp = __builtin_amdgcn_fdot2(e2, ones2, zp, false);
#else
                zp += (float)e2.x + (float)e2.y;
#endif
                wbu.h[p] = e2;
            }
            half8 af = wbu.h8;
#pragma unroll
            for (int ct = 0; ct < 4; ct++) {
                half8 bf = *(const half8*)&vts[cur][(ct * 16 + l15) * VT_STRIDE + kk * 32 + quad * 8];
                acc[ct] = __builtin_amdgcn_mfma_f32_16x16x32_f16(af, bf, acc[ct], 0, 0, 0);
            }
        }
        if (mt < 7) mcur = mnext;
    }

    // Z reduction across quads, distribute 1/Z by shfl
    zp += __shfl_xor(zp, 16);
    zp += __shfl_xor(zp, 32);
    const float rzown = 1.0f / zp;

    // epilogue: out[b][n][h*64+o] = relu(acc / Z)
#pragma unroll
    for (int r = 0; r < 4; r++) {
        const int rr = wave * 16 + quad * 4 + r;
        const float rz = __shfl(rzown, quad * 20 + r);
#pragma unroll
        for (int ct = 0; ct < 4; ct++) {
            float v = acc[ct][r] * rz;
            v = v > 0.f ? v : 0.f;
            out[((size_t)b * NN + n0 + rr) * HS + h * SUP + ct * 16 + l15] = v;
        }
    }
}

// ---------------------------------------------------------------------------
extern "C" void kernel_launch(void* const* d_in, const int* in_sizes, int n_in,
                              void* d_out, int out_size, void* d_ws, size_t ws_size,
                              hipStream_t stream) {
    const float* A  = (const float*)d_in[0];
    const float* X  = (const float*)d_in[1];
    const float* W  = (const float*)d_in[2];
    const float* w1 = (const float*)d_in[3];
    const float* b1 = (const float*)d_in[4];
    const float* w2 = (const float*)d_in[5];
    const float* b2 = (const float*)d_in[6];
    float* out = (float*)d_out;

    char* ws = (char*)d_ws;
    _Float16*      Wt     = (_Float16*)(ws);                  // 524288 B
    _Float16*      Pt     = (_Float16*)(ws + 524288);         // 8388608 B
    float*         s_g    = (float*)(ws + 8912896);           // 262144 B
    float*         t_g    = (float*)(ws + 9175040);           // 262144 B
    float*         tmax16 = (float*)(ws + 9437184);           // 4096 B
    unsigned char* Am     = (unsigned char*)(ws + 9441280);   // 1048576 B

    hipLaunchKernelGGL(kW, dim3(64), dim3(256), 0, stream, W, Wt);
    hipLaunchKernelGGL(k1_proj, dim3(768), dim3(256), 0, stream,
                       X, Wt, A, Am, w1, b1, w2, b2, Pt, s_g, t_g, tmax16);
    hipLaunchKernelGGL(k2_attn, dim3(512), dim3(512), 0, stream,
                       Am, Pt, s_g, t_g, tmax16, out);
}